// Round 14
// baseline (424.763 us; speedup 1.0000x reference)
//
#include <hip/hip_runtime.h>

typedef short v8s __attribute__((ext_vector_type(8)));
typedef float v4f __attribute__((ext_vector_type(4)));
typedef unsigned short v4us __attribute__((ext_vector_type(4)));

__device__ __forceinline__ unsigned short f2bf(float x) {
  union { float f; unsigned int u; } c; c.f = x;
  unsigned int u = c.u;
  return (unsigned short)((u + 0x7fffu + ((u >> 16) & 1u)) >> 16);
}
__device__ __forceinline__ float bflo(unsigned int u) {   // low bf16 of u32 -> f32
  union { unsigned int u; float f; } c; c.u = u << 16; return c.f;
}
__device__ __forceinline__ float bfhi(unsigned int u) {   // high bf16 of u32 -> f32
  union { unsigned int u; float f; } c; c.u = u & 0xffff0000u; return c.f;
}
__device__ __forceinline__ ushort2 pk(float2 v) {
  ushort2 p; p.x = f2bf(v.x); p.y = f2bf(v.y); return p;
}
__device__ __forceinline__ v4us pk4(v4f v) {
  v4us r; r[0] = f2bf(v[0]); r[1] = f2bf(v[1]); r[2] = f2bf(v[2]); r[3] = f2bf(v[3]);
  return r;
}

// Pack [Wl|Wr] into 256-wide MFMA A-operand fragments:
// wpk[kc*8192 + n*32 + kk], n in [0,256): 0:128 = Wl, 128:256 = Wr.
// k >= K entries are ZERO (K-pad relies on it).
__device__ __forceinline__ void pack2_dev(const float* __restrict__ Wl,
                                          const float* __restrict__ Wr,
                                          unsigned short* __restrict__ wpk,
                                          int K, int tot, int i) {
  if (i >= tot) return;
  const int kk = i & 31, n = (i >> 5) & 255, kc = i >> 13;
  const int k = kc * 32 + kk;
  float v = 0.f;
  if (k < K) v = (n < 128) ? Wl[k * 128 + n] : Wr[k * 128 + (n - 128)];
  wpk[i] = f2bf(v);
}

// ---------- ONE setup dispatch: zero degi | 2 combined weight packs | BN-fold | sentinel
__global__ void setup_k(const float* __restrict__ g1, const float* __restrict__ be1,
                        const float* __restrict__ rm1, const float* __restrict__ rv1,
                        const float* __restrict__ b1,
                        const float* __restrict__ g2, const float* __restrict__ be2,
                        const float* __restrict__ rm2, const float* __restrict__ rv2,
                        const float* __restrict__ b2,
                        const float* __restrict__ W1l, const float* __restrict__ W1r,
                        const float* __restrict__ W2l, const float* __restrict__ W2r,
                        float* __restrict__ s1, float* __restrict__ t1,
                        float* __restrict__ s2, float* __restrict__ t2,
                        unsigned short* __restrict__ wp1, unsigned short* __restrict__ wp2,
                        unsigned short* __restrict__ bufA, int* __restrict__ degi,
                        int N, int NZB) {
  const int b = blockIdx.x, tid = threadIdx.x;
  if (b < NZB) {
    const int i = b * 256 + tid;
    if (i < N) degi[i] = 0;
    return;
  }
  int r = b - NZB;
  if (r < 160) { pack2_dev(W1l, W1r, wp1, 130, 5 * 8192, r * 256 + tid); return; }
  r -= 160;
  if (r < 128) { pack2_dev(W2l, W2r, wp2, 128, 4 * 8192, r * 256 + tid); return; }
  // final block: BN fold + sentinel
  if (tid < 128) {
    float sv = g1[tid] * rsqrtf(rv1[tid] + 1e-5f);
    s1[tid] = sv; t1[tid] = (b1[tid] - rm1[tid]) * sv + be1[tid];
    float sw = g2[tid] * rsqrtf(rv2[tid] + 1e-5f);
    s2[tid] = sw; t2[tid] = (b2[tid] - rm2[tid]) * sw + be2[tid];
  }
  if (tid < 64) ((unsigned int*)(bufA + (long)N * 128))[tid] = 0u;
}

// ---------- CSR: scan1 (per-1024 block sums), scan3' (absorbs scan2), fill ----------
__global__ __launch_bounds__(256) void scan1_k(const int* __restrict__ degi,
                                               int* __restrict__ rowptr,
                                               int* __restrict__ bsum, int N) {
  __shared__ int sd[256];
  const int t = threadIdx.x;
  const int base = blockIdx.x * 1024 + t * 4;
  int v[4];
#pragma unroll
  for (int j = 0; j < 4; ++j) v[j] = (base + j < N) ? degi[base + j] : 0;
  const int tot = v[0] + v[1] + v[2] + v[3];
  sd[t] = tot;
  __syncthreads();
  for (int off = 1; off < 256; off <<= 1) {
    int o = (t >= off) ? sd[t - off] : 0;
    __syncthreads();
    sd[t] += o;
    __syncthreads();
  }
  int e = sd[t] - tot;
#pragma unroll
  for (int j = 0; j < 4; ++j) {
    if (base + j < N) rowptr[base + j] = e;
    e += v[j];
  }
  if (t == 255) bsum[blockIdx.x] = sd[255];
}
// scan3': each block's 256 indices live in ONE 1024-chunk (chunk = blockIdx>>2).
__global__ __launch_bounds__(256) void scan3_k(int* __restrict__ rowptr,
                                               int* __restrict__ cursor,
                                               const int* __restrict__ bsum,
                                               int N, int E) {
  __shared__ int sd[256];
  const int t = threadIdx.x;
  const int chunk = blockIdx.x >> 2;     // nb1k <= 256 assumed
  sd[t] = (t < chunk) ? bsum[t] : 0;
  __syncthreads();
  for (int off = 128; off >= 1; off >>= 1) {
    if (t < off) sd[t] += sd[t + off];
    __syncthreads();
  }
  const int S = sd[0];
  const int i = blockIdx.x * 256 + t;
  if (i < N) {
    const int v = rowptr[i] + S;
    rowptr[i] = v;
    cursor[i] = v;
  } else if (i == N) {
    rowptr[N] = E;
  }
}
__global__ void fill_k(const int* __restrict__ src, const int* __restrict__ dst,
                       int* __restrict__ cursor, int* __restrict__ nbr, int E) {
  int i = blockIdx.x * 256 + threadIdx.x;
  if (i < E) {
    int p = atomicAdd(&cursor[dst[i]], 1);
    nbr[p] = src[i];
  }
}

// ---------- FUSED dispatch: 8-WAVE L1 GEMM (P1l|P1r = x @ [W1l|W1r]) + edge count ----
// 512 threads, 64-row x 256-col tile. Wave w: node-half (w&1)*32, feature-64-block
// (w>>1). acc[2][4] = 32 AGPR/thread (half of the 4-wave form) -> higher waves/SIMD.
// Staging: linear-coalesced fp32 float4 sweep -> bf16 LDS via exact magic-div scatter.
// Blocks [ngb, ...): count degi (independent; hides under the GEMM).
__global__ __launch_bounds__(512) void gemmc_k(const float* __restrict__ Asrc,
                                               const unsigned short* __restrict__ wpk,
                                               unsigned short* __restrict__ Ol,
                                               unsigned short* __restrict__ Or,
                                               const int* __restrict__ dst,
                                               int* __restrict__ degi,
                                               int N, int E, int ngb) {
  constexpr int KC = 5;
  __shared__ __align__(16) unsigned short a_s[64][168];
  const int tid = threadIdx.x;

  if ((int)blockIdx.x >= ngb) {   // ---- edge-count part ----
    const int i = ((int)blockIdx.x - ngb) * 512 + tid;
    if (i < E) atomicAdd(&degi[dst[i]], 1);
    return;
  }

  const int node0 = blockIdx.x * 64;
  {  // zero pad cols [130,136) and [136,168)
    v8s z = {0, 0, 0, 0, 0, 0, 0, 0};
    if (tid < 256) *(v8s*)&a_s[tid >> 2][136 + (tid & 3) * 8] = z;
    if (tid < 192) {
      const int r3 = tid / 3, p3 = tid - 3 * r3;
      *(unsigned int*)&a_s[r3][130 + 2 * p3] = 0u;
    }
  }
  const float* xb = Asrc + (long)node0 * 130;
  if (node0 + 64 <= N) {      // full tile: unguarded linear float4 sweep (2080 units)
    float4 v[5];
#pragma unroll
    for (int i = 0; i < 5; ++i) {
      const int g = i * 512 + tid;
      if (g < 2080) v[i] = *(const float4*)(xb + 4 * g);
    }
#pragma unroll
    for (int i = 0; i < 5; ++i) {
      const int g = i * 512 + tid;
      if (g < 2080) {
        const int p0 = 2 * g, p1 = 2 * g + 1;
        const int r0_ = (p0 * 4033) >> 18, r1_ = (p1 * 4033) >> 18;
        const int c0_ = p0 - 65 * r0_, c1_ = p1 - 65 * r1_;
        *(ushort2*)&a_s[r0_][2 * c0_] = pk(make_float2(v[i].x, v[i].y));
        *(ushort2*)&a_s[r1_][2 * c1_] = pk(make_float2(v[i].z, v[i].w));
      }
    }
  } else {                    // partial tail tile: per-pair guarded float2
    for (int i = 0; i < 5; ++i) {
      const int g = i * 512 + tid;
      if (g < 2080) {
#pragma unroll
        for (int h = 0; h < 2; ++h) {
          const int p = 2 * g + h;
          const int r = (p * 4033) >> 18;
          const int c = p - 65 * r;
          float2 vv = make_float2(0.f, 0.f);
          if (node0 + r < N)
            vv = *(const float2*)(Asrc + (long)(node0 + r) * 130 + 2 * c);
          *(ushort2*)&a_s[r][2 * c] = pk(vv);
        }
      }
    }
  }
  __syncthreads();

  const int wave = tid >> 6, lane = tid & 63;
  const int quad = lane >> 4, l16 = lane & 15;
  const int nh  = wave & 1;      // node half: rows nh*32 .. nh*32+31
  const int fhb = wave >> 1;     // feature 64-block: cols fhb*64 .. +63
  v4f acc[2][4];
#pragma unroll
  for (int mt = 0; mt < 2; ++mt)
#pragma unroll
    for (int nt = 0; nt < 4; ++nt) acc[mt][nt] = (v4f){0.f, 0.f, 0.f, 0.f};

  const unsigned short* wb = wpk + (fhb * 64 + l16) * 32 + quad * 8;
#pragma unroll
  for (int kc = 0; kc < KC; ++kc) {
    v8s wf[4];
#pragma unroll
    for (int nt = 0; nt < 4; ++nt)
      wf[nt] = *(const v8s*)(wb + kc * 8192 + nt * 512);
#pragma unroll
    for (int mt = 0; mt < 2; ++mt) {
      v8s nf = *(const v8s*)(&a_s[nh * 32 + mt * 16 + l16][kc * 32 + quad * 8]);
#pragma unroll
      for (int nt = 0; nt < 4; ++nt)
        acc[mt][nt] = __builtin_amdgcn_mfma_f32_16x16x32_bf16(wf[nt], nf, acc[mt][nt], 0, 0, 0);
    }
  }

  // D: col=l16 -> node, row=quad*4+r -> feature. fhb 0,1 -> Ol; 2,3 -> Or.
  unsigned short* ob = (fhb < 2) ? Ol : Or;
  const int cb = (fhb & 1) * 64;
#pragma unroll
  for (int mt = 0; mt < 2; ++mt) {
    const int rw = node0 + nh * 32 + mt * 16 + l16;
    if (rw < N) {
#pragma unroll
      for (int nt = 0; nt < 4; ++nt)
        *(v4us*)(ob + (long)rw * 128 + cb + nt * 16 + quad * 4) = pk4(acc[mt][nt]);
    }
  }
}

// ---------- 8-WAVE 256-wide GEMM, bf16 source (layer 2): P2l|P2r = h1 @ [W2l|W2r] ----
__global__ __launch_bounds__(512) void gemmB_k(const unsigned short* __restrict__ Asrc,
                                               const unsigned short* __restrict__ wpk,
                                               unsigned short* __restrict__ Ol,
                                               unsigned short* __restrict__ Or, int N) {
  constexpr int KC = 4;
  __shared__ __align__(16) unsigned short a_s[64][136];
  const int tid = threadIdx.x;
  const int node0 = blockIdx.x * 64;

  const unsigned short* hb = Asrc + (long)node0 * 128;
  v8s v[2];
#pragma unroll
  for (int i = 0; i < 2; ++i) {   // 1024 v8s units over 512 threads
    const int u = i * 512 + tid;
    const int r = u >> 4;
    v[i] = (v8s){0, 0, 0, 0, 0, 0, 0, 0};
    if (node0 + r < N) v[i] = *(const v8s*)(hb + 8 * u);
  }
#pragma unroll
  for (int i = 0; i < 2; ++i) {
    const int u = i * 512 + tid;
    *(v8s*)&a_s[u >> 4][(u & 15) * 8] = v[i];
  }
  __syncthreads();

  const int wave = tid >> 6, lane = tid & 63;
  const int quad = lane >> 4, l16 = lane & 15;
  const int nh  = wave & 1;
  const int fhb = wave >> 1;
  v4f acc[2][4];
#pragma unroll
  for (int mt = 0; mt < 2; ++mt)
#pragma unroll
    for (int nt = 0; nt < 4; ++nt) acc[mt][nt] = (v4f){0.f, 0.f, 0.f, 0.f};

  const unsigned short* wb = wpk + (fhb * 64 + l16) * 32 + quad * 8;
#pragma unroll
  for (int kc = 0; kc < KC; ++kc) {
    v8s wf[4];
#pragma unroll
    for (int nt = 0; nt < 4; ++nt)
      wf[nt] = *(const v8s*)(wb + kc * 8192 + nt * 512);
#pragma unroll
    for (int mt = 0; mt < 2; ++mt) {
      v8s nf = *(const v8s*)(&a_s[nh * 32 + mt * 16 + l16][kc * 32 + quad * 8]);
#pragma unroll
      for (int nt = 0; nt < 4; ++nt)
        acc[mt][nt] = __builtin_amdgcn_mfma_f32_16x16x32_bf16(wf[nt], nf, acc[mt][nt], 0, 0, 0);
    }
  }

  unsigned short* ob = (fhb < 2) ? Ol : Or;
  const int cb = (fhb & 1) * 64;
#pragma unroll
  for (int mt = 0; mt < 2; ++mt) {
    const int rw = node0 + nh * 32 + mt * 16 + l16;
    if (rw < N) {
#pragma unroll
      for (int nt = 0; nt < 4; ++nt)
        *(v4us*)(ob + (long)rw * 128 + cb + nt * 16 + quad * 4) = pk4(acc[mt][nt]);
    }
  }
}

// ---------- light aggregate: out = relu((mean(gsrc[nbr]) + rsrc[node]) * s + t) ----
// 8 rows/wave, chunk-of-4 with per-row uniform skip; CSR state wave-uniform.
// In-place allowed: out may alias rsrc (own-row read data-depends before the write).
template<bool OUTF32>
__global__ __launch_bounds__(256) void spmmL_k(const unsigned short* __restrict__ gsrc,
                                               const unsigned short* __restrict__ rsrc,
                                               const int* __restrict__ rowptr,
                                               const int* __restrict__ nbr,
                                               const float* __restrict__ sc,
                                               const float* __restrict__ tc,
                                               void* __restrict__ out, int N, int E) {
  const int tid = threadIdx.x;
  const int lane = tid & 63;
  const int wu = __builtin_amdgcn_readfirstlane(tid >> 6);
  const int nb = blockIdx.x * 32 + wu * 8;

  int r0[8], d[8];
#pragma unroll
  for (int r = 0; r < 8; ++r) {
    const int i0 = min(nb + r, N);
    const int i1 = min(nb + r + 1, N);
    r0[r] = rowptr[i0];
    d[r] = (nb + r < N) ? (rowptr[i1] - r0[r]) : 0;
  }
  int dm = 0;
#pragma unroll
  for (int r = 0; r < 8; ++r) dm = max(dm, d[r]);

  float2 a[8];
#pragma unroll
  for (int r = 0; r < 8; ++r) a[r] = make_float2(0.f, 0.f);

  const int lofs = lane << 1;
  for (int e0 = 0; e0 < dm; e0 += 4) {
    unsigned int u[8][4];
#pragma unroll
    for (int r = 0; r < 8; ++r) {
      if (e0 < d[r]) {                                    // uniform scalar skip
#pragma unroll
        for (int j = 0; j < 4; ++j) {
          const int e = e0 + j;
          const int nv = nbr[min(r0[r] + e, E - 1)];      // uniform s_load (clamped)
          const int idx = (e < d[r]) ? nv : N;            // uniform -> sentinel row
          u[r][j] = *(const unsigned int*)(gsrc + ((long)idx << 7) + lofs);
        }
      }
    }
#pragma unroll
    for (int r = 0; r < 8; ++r) {
      if (e0 < d[r]) {
#pragma unroll
        for (int j = 0; j < 4; ++j) {
          a[r].x += bflo(u[r][j]);
          a[r].y += bfhi(u[r][j]);
        }
      }
    }
  }

  const float2 sv = *(const float2*)(sc + lofs);
  const float2 tv = *(const float2*)(tc + lofs);
#pragma unroll
  for (int r = 0; r < 8; ++r) {
    if (nb + r < N) {
      const float inv = 1.0f / fmaxf((float)d[r], 1.0f);
      const unsigned int ur = *(const unsigned int*)(rsrc + ((long)(nb + r) << 7) + lofs);
      float yx = fmaxf((a[r].x * inv + bflo(ur)) * sv.x + tv.x, 0.f);
      float yy = fmaxf((a[r].y * inv + bfhi(ur)) * sv.y + tv.y, 0.f);
      if (OUTF32) {
        *(float2*)((float*)out + (long)(nb + r) * 128 + lofs) = make_float2(yx, yy);
      } else {
        *(ushort2*)((unsigned short*)out + (long)(nb + r) * 128 + lofs) =
            pk(make_float2(yx, yy));
      }
    }
  }
}

extern "C" void kernel_launch(void* const* d_in, const int* in_sizes, int n_in,
                              void* d_out, int out_size, void* d_ws, size_t ws_size,
                              hipStream_t stream) {
  const float* x   = (const float*)d_in[0];
  const int*   ei  = (const int*)d_in[1];
  const float* W1l = (const float*)d_in[2];
  const float* b1  = (const float*)d_in[3];
  const float* W1r = (const float*)d_in[4];
  const float* g1  = (const float*)d_in[5];
  const float* be1 = (const float*)d_in[6];
  const float* rm1 = (const float*)d_in[7];
  const float* rv1 = (const float*)d_in[8];
  const float* W2l = (const float*)d_in[9];
  const float* b2  = (const float*)d_in[10];
  const float* W2r = (const float*)d_in[11];
  const float* g2  = (const float*)d_in[12];
  const float* be2 = (const float*)d_in[13];
  const float* rm2 = (const float*)d_in[14];
  const float* rv2 = (const float*)d_in[15];

  const int E = in_sizes[1] / 2;
  const int N = in_sizes[0] / 130;
  const int* src = ei;
  const int* dst = ei + E;

  // workspace carve (~158 MB)
  unsigned short* bufA = (unsigned short*)d_ws;            // P1l -> P2l (gather target, sentinel row N)
  unsigned short* bufB = bufA + (size_t)(N + 1) * 128;     // P1r -> h1 (in-place)
  unsigned short* bufC = bufB + (size_t)(N + 1) * 128;     // P2r
  unsigned short* wp1  = bufC + (size_t)N * 128;           // 5*8192
  unsigned short* wp2  = wp1 + 5 * 8192;                   // 4*8192
  float* s1 = (float*)(wp2 + 4 * 8192);
  float* t1 = s1 + 128;
  float* s2 = t1 + 128;
  float* t2 = s2 + 128;
  int* degi   = (int*)(t2 + 128);   // N (reused as cursor)
  int* rowptr = degi + N;           // N+1
  int* bsum   = rowptr + N + 1;     // 256
  int* nbr    = bsum + 256;         // E

  const int NZB = (N + 255) / 256;
  const int ngb = (N + 63) / 64;
  const int ecb = (E + 511) / 512;  // edge-count blocks at 512 threads
  const int nsb = (N + 31) / 32;
  const int nb1k = (N + 1023) / 1024;

  // 1) setup: zero degi + 2 combined packs + bn_fold + sentinel
  hipLaunchKernelGGL(setup_k, dim3(NZB + 288 + 1), dim3(256), 0, stream,
                     g1, be1, rm1, rv1, b1, g2, be2, rm2, rv2, b2,
                     W1l, W1r, W2l, W2r, s1, t1, s2, t2,
                     wp1, wp2, bufA, degi, N, NZB);

  // 2) fused: P1l|P1r = x @ [W1l|W1r] (8-wave)  ||  edge count into degi
  hipLaunchKernelGGL(gemmc_k, dim3(ngb + ecb), dim3(512), 0, stream,
                     x, wp1, bufA, bufB, dst, degi, N, E, ngb);

  // 3) CSR: scan1 -> scan3' -> fill
  hipLaunchKernelGGL(scan1_k, dim3(nb1k), dim3(256), 0, stream, degi, rowptr, bsum, N);
  hipLaunchKernelGGL(scan3_k, dim3((N + 256) / 256), dim3(256), 0, stream,
                     rowptr, degi, bsum, N, E);
  hipLaunchKernelGGL(fill_k, dim3((E + 255) / 256), dim3(256), 0, stream,
                     src, dst, degi, nbr, E);

  // 4) L1 aggregate: h1 = relu((mean(P1l[nbr]) + P1r)*s1 + t1')  (in-place over bufB)
  hipLaunchKernelGGL((spmmL_k<false>), dim3(nsb), dim3(256), 0, stream,
                     bufA, bufB, rowptr, nbr, s1, t1, (void*)bufB, N, E);
  // 5) L2 dense: P2l|P2r = h1 @ [W2l|W2r] (8-wave)
  hipLaunchKernelGGL(gemmB_k, dim3(ngb), dim3(512), 0, stream,
                     bufB, wp2, bufA, bufC, N);
  // 6) L2 aggregate: out = relu((mean(P2l[nbr]) + P2r)*s2 + t2') -> d_out fp32
  hipLaunchKernelGGL((spmmL_k<true>), dim3(nsb), dim3(256), 0, stream,
                     bufA, bufC, rowptr, nbr, s2, t2, d_out, N, E);
}

// Round 15
// 413.509 us; speedup vs baseline: 1.0272x; 1.0272x over previous
//
#include <hip/hip_runtime.h>

typedef short v8s __attribute__((ext_vector_type(8)));
typedef float v4f __attribute__((ext_vector_type(4)));
typedef unsigned short v4us __attribute__((ext_vector_type(4)));

__device__ __forceinline__ unsigned short f2bf(float x) {
  union { float f; unsigned int u; } c; c.f = x;
  unsigned int u = c.u;
  return (unsigned short)((u + 0x7fffu + ((u >> 16) & 1u)) >> 16);
}
__device__ __forceinline__ float bflo(unsigned int u) {   // low bf16 of u32 -> f32
  union { unsigned int u; float f; } c; c.u = u << 16; return c.f;
}
__device__ __forceinline__ float bfhi(unsigned int u) {   // high bf16 of u32 -> f32
  union { unsigned int u; float f; } c; c.u = u & 0xffff0000u; return c.f;
}
__device__ __forceinline__ ushort2 pk(float2 v) {
  ushort2 p; p.x = f2bf(v.x); p.y = f2bf(v.y); return p;
}
__device__ __forceinline__ v4us pk4(v4f v) {
  v4us r; r[0] = f2bf(v[0]); r[1] = f2bf(v[1]); r[2] = f2bf(v[2]); r[3] = f2bf(v[3]);
  return r;
}

// Pack [Wl|Wr] into 256-wide MFMA A-operand fragments:
// wpk[kc*8192 + n*32 + kk], n in [0,256): 0:128 = Wl, 128:256 = Wr.
// k >= K entries are ZERO (K-pad relies on it).
__device__ __forceinline__ void pack2_dev(const float* __restrict__ Wl,
                                          const float* __restrict__ Wr,
                                          unsigned short* __restrict__ wpk,
                                          int K, int tot, int i) {
  if (i >= tot) return;
  const int kk = i & 31, n = (i >> 5) & 255, kc = i >> 13;
  const int k = kc * 32 + kk;
  float v = 0.f;
  if (k < K) v = (n < 128) ? Wl[k * 128 + n] : Wr[k * 128 + (n - 128)];
  wpk[i] = f2bf(v);
}

// ---------- ONE setup dispatch: zero degi | 2 combined weight packs | BN-fold | sentinel
__global__ void setup_k(const float* __restrict__ g1, const float* __restrict__ be1,
                        const float* __restrict__ rm1, const float* __restrict__ rv1,
                        const float* __restrict__ b1,
                        const float* __restrict__ g2, const float* __restrict__ be2,
                        const float* __restrict__ rm2, const float* __restrict__ rv2,
                        const float* __restrict__ b2,
                        const float* __restrict__ W1l, const float* __restrict__ W1r,
                        const float* __restrict__ W2l, const float* __restrict__ W2r,
                        float* __restrict__ s1, float* __restrict__ t1,
                        float* __restrict__ s2, float* __restrict__ t2,
                        unsigned short* __restrict__ wp1, unsigned short* __restrict__ wp2,
                        unsigned short* __restrict__ bufA, int* __restrict__ degi,
                        int N, int NZB) {
  const int b = blockIdx.x, tid = threadIdx.x;
  if (b < NZB) {
    const int i = b * 256 + tid;
    if (i < N) degi[i] = 0;
    return;
  }
  int r = b - NZB;
  if (r < 160) { pack2_dev(W1l, W1r, wp1, 130, 5 * 8192, r * 256 + tid); return; }
  r -= 160;
  if (r < 128) { pack2_dev(W2l, W2r, wp2, 128, 4 * 8192, r * 256 + tid); return; }
  // final block: BN fold + sentinel
  if (tid < 128) {
    float sv = g1[tid] * rsqrtf(rv1[tid] + 1e-5f);
    s1[tid] = sv; t1[tid] = (b1[tid] - rm1[tid]) * sv + be1[tid];
    float sw = g2[tid] * rsqrtf(rv2[tid] + 1e-5f);
    s2[tid] = sw; t2[tid] = (b2[tid] - rm2[tid]) * sw + be2[tid];
  }
  if (tid < 64) ((unsigned int*)(bufA + (long)N * 128))[tid] = 0u;
}

// ---------- CSR: scan1 (per-1024 block sums), scan3' (absorbs scan2), fill ----------
__global__ __launch_bounds__(256) void scan1_k(const int* __restrict__ degi,
                                               int* __restrict__ rowptr,
                                               int* __restrict__ bsum, int N) {
  __shared__ int sd[256];
  const int t = threadIdx.x;
  const int base = blockIdx.x * 1024 + t * 4;
  int v[4];
#pragma unroll
  for (int j = 0; j < 4; ++j) v[j] = (base + j < N) ? degi[base + j] : 0;
  const int tot = v[0] + v[1] + v[2] + v[3];
  sd[t] = tot;
  __syncthreads();
  for (int off = 1; off < 256; off <<= 1) {
    int o = (t >= off) ? sd[t - off] : 0;
    __syncthreads();
    sd[t] += o;
    __syncthreads();
  }
  int e = sd[t] - tot;
#pragma unroll
  for (int j = 0; j < 4; ++j) {
    if (base + j < N) rowptr[base + j] = e;
    e += v[j];
  }
  if (t == 255) bsum[blockIdx.x] = sd[255];
}
// scan3': each block's 256 indices live in ONE 1024-chunk (chunk = blockIdx>>2).
__global__ __launch_bounds__(256) void scan3_k(int* __restrict__ rowptr,
                                               int* __restrict__ cursor,
                                               const int* __restrict__ bsum,
                                               int N, int E) {
  __shared__ int sd[256];
  const int t = threadIdx.x;
  const int chunk = blockIdx.x >> 2;     // nb1k <= 256 assumed
  sd[t] = (t < chunk) ? bsum[t] : 0;
  __syncthreads();
  for (int off = 128; off >= 1; off >>= 1) {
    if (t < off) sd[t] += sd[t + off];
    __syncthreads();
  }
  const int S = sd[0];
  const int i = blockIdx.x * 256 + t;
  if (i < N) {
    const int v = rowptr[i] + S;
    rowptr[i] = v;
    cursor[i] = v;
  } else if (i == N) {
    rowptr[N] = E;
  }
}
__global__ void fill_k(const int* __restrict__ src, const int* __restrict__ dst,
                       int* __restrict__ cursor, int* __restrict__ nbr, int E) {
  int i = blockIdx.x * 256 + threadIdx.x;
  if (i < E) {
    int p = atomicAdd(&cursor[dst[i]], 1);
    nbr[p] = src[i];
  }
}

// ---------- FUSED dispatch: L1 dense GEMM (P1l|P1r = x @ [W1l|W1r]) + edge count ----
// Single-tile form (best measured): linear-coalesced fp32 staging -> LDS bf16,
// swapped MFMA operands (A-op = weights, B-op = nodes), 8-B coalesced stores.
// Blocks [ngb, ...): count degi. Independent work; atomics hide under the GEMM.
__global__ __launch_bounds__(256) void gemmc_k(const float* __restrict__ Asrc,
                                               const unsigned short* __restrict__ wpk,
                                               unsigned short* __restrict__ Ol,
                                               unsigned short* __restrict__ Or,
                                               const int* __restrict__ dst,
                                               int* __restrict__ degi,
                                               int N, int E, int ngb) {
  constexpr int KC = 5;
  __shared__ __align__(16) unsigned short a_s[64][168];
  const int tid = threadIdx.x;

  if ((int)blockIdx.x >= ngb) {   // ---- edge-count part ----
    const int i = ((int)blockIdx.x - ngb) * 256 + tid;
    if (i < E) atomicAdd(&degi[dst[i]], 1);
    return;
  }

  const int node0 = blockIdx.x * 64;
  {  // zero pad cols [130,136) and [136,168)
    const int zr = tid >> 2, zq = tid & 3;
    v8s z = {0, 0, 0, 0, 0, 0, 0, 0};
    *(v8s*)&a_s[zr][136 + zq * 8] = z;
    if (tid < 192) {
      const int r3 = tid / 3, p3 = tid - 3 * r3;
      *(unsigned int*)&a_s[r3][130 + 2 * p3] = 0u;
    }
  }
  const float* xb = Asrc + (long)node0 * 130;
  if (node0 + 64 <= N) {      // full tile: unguarded linear float4 sweep
    float4 v[9];
#pragma unroll
    for (int i = 0; i < 9; ++i) {
      const int g = i * 256 + tid;
      if (g < 2080) v[i] = *(const float4*)(xb + 4 * g);
    }
#pragma unroll
    for (int i = 0; i < 9; ++i) {
      const int g = i * 256 + tid;
      if (g < 2080) {
        const int p0 = 2 * g, p1 = 2 * g + 1;
        const int r0_ = (p0 * 4033) >> 18, r1_ = (p1 * 4033) >> 18;
        const int c0_ = p0 - 65 * r0_, c1_ = p1 - 65 * r1_;
        *(ushort2*)&a_s[r0_][2 * c0_] = pk(make_float2(v[i].x, v[i].y));
        *(ushort2*)&a_s[r1_][2 * c1_] = pk(make_float2(v[i].z, v[i].w));
      }
    }
  } else {                    // partial tail tile: per-pair guarded float2
    for (int i = 0; i < 9; ++i) {
      const int g = i * 256 + tid;
      if (g < 2080) {
#pragma unroll
        for (int h = 0; h < 2; ++h) {
          const int p = 2 * g + h;
          const int r = (p * 4033) >> 18;
          const int c = p - 65 * r;
          float2 vv = make_float2(0.f, 0.f);
          if (node0 + r < N)
            vv = *(const float2*)(Asrc + (long)(node0 + r) * 130 + 2 * c);
          *(ushort2*)&a_s[r][2 * c] = pk(vv);
        }
      }
    }
  }
  __syncthreads();

  const int wave = tid >> 6, lane = tid & 63;
  const int quad = lane >> 4, l16 = lane & 15;
  v4f acc[4][4];
#pragma unroll
  for (int mt = 0; mt < 4; ++mt)
#pragma unroll
    for (int nt = 0; nt < 4; ++nt) acc[mt][nt] = (v4f){0.f, 0.f, 0.f, 0.f};

  const unsigned short* wb = wpk + (wave * 64 + l16) * 32 + quad * 8;
#pragma unroll
  for (int kc = 0; kc < KC; ++kc) {
    v8s wf[4];
#pragma unroll
    for (int nt = 0; nt < 4; ++nt)
      wf[nt] = *(const v8s*)(wb + kc * 8192 + nt * 512);
#pragma unroll
    for (int mt = 0; mt < 4; ++mt) {
      v8s nf = *(const v8s*)(&a_s[mt * 16 + l16][kc * 32 + quad * 8]);
#pragma unroll
      for (int nt = 0; nt < 4; ++nt)
        acc[mt][nt] = __builtin_amdgcn_mfma_f32_16x16x32_bf16(wf[nt], nf, acc[mt][nt], 0, 0, 0);
    }
  }

  // D: col=l16 -> node, row=quad*4+r -> feature. waves 0,1 -> Ol; 2,3 -> Or.
  unsigned short* ob = (wave < 2) ? Ol : Or;
  const int cb = (wave & 1) * 64;
#pragma unroll
  for (int mt = 0; mt < 4; ++mt) {
    const int rw = node0 + mt * 16 + l16;
    if (rw < N) {
#pragma unroll
      for (int nt = 0; nt < 4; ++nt)
        *(v4us*)(ob + (long)rw * 128 + cb + nt * 16 + quad * 4) = pk4(acc[mt][nt]);
    }
  }
}

// ---------- 256-wide dense GEMM, bf16 source (layer 2): P2l|P2r = h1 @ [W2l|W2r] ----
__global__ __launch_bounds__(256) void gemmB_k(const unsigned short* __restrict__ Asrc,
                                               const unsigned short* __restrict__ wpk,
                                               unsigned short* __restrict__ Ol,
                                               unsigned short* __restrict__ Or, int N) {
  constexpr int KC = 4;
  __shared__ __align__(16) unsigned short a_s[64][136];
  const int tid = threadIdx.x;
  const int node0 = blockIdx.x * 64;

  const unsigned short* hb = Asrc + (long)node0 * 128;
  v8s v[KC];
#pragma unroll
  for (int i = 0; i < KC; ++i) {
    const int u = i * 256 + tid;
    const int r = u >> 4;
    v[i] = (v8s){0, 0, 0, 0, 0, 0, 0, 0};
    if (node0 + r < N) v[i] = *(const v8s*)(hb + 8 * u);
  }
#pragma unroll
  for (int i = 0; i < KC; ++i) {
    const int u = i * 256 + tid;
    *(v8s*)&a_s[u >> 4][(u & 15) * 8] = v[i];
  }
  __syncthreads();

  const int wave = tid >> 6, lane = tid & 63;
  const int quad = lane >> 4, l16 = lane & 15;
  v4f acc[4][4];
#pragma unroll
  for (int mt = 0; mt < 4; ++mt)
#pragma unroll
    for (int nt = 0; nt < 4; ++nt) acc[mt][nt] = (v4f){0.f, 0.f, 0.f, 0.f};

  const unsigned short* wb = wpk + (wave * 64 + l16) * 32 + quad * 8;
#pragma unroll
  for (int kc = 0; kc < KC; ++kc) {
    v8s wf[4];
#pragma unroll
    for (int nt = 0; nt < 4; ++nt)
      wf[nt] = *(const v8s*)(wb + kc * 8192 + nt * 512);
#pragma unroll
    for (int mt = 0; mt < 4; ++mt) {
      v8s nf = *(const v8s*)(&a_s[mt * 16 + l16][kc * 32 + quad * 8]);
#pragma unroll
      for (int nt = 0; nt < 4; ++nt)
        acc[mt][nt] = __builtin_amdgcn_mfma_f32_16x16x32_bf16(wf[nt], nf, acc[mt][nt], 0, 0, 0);
    }
  }

  unsigned short* ob = (wave < 2) ? Ol : Or;
  const int cb = (wave & 1) * 64;
#pragma unroll
  for (int mt = 0; mt < 4; ++mt) {
    const int rw = node0 + mt * 16 + l16;
    if (rw < N) {
#pragma unroll
      for (int nt = 0; nt < 4; ++nt)
        *(v4us*)(ob + (long)rw * 128 + cb + nt * 16 + quad * 4) = pk4(acc[mt][nt]);
    }
  }
}

// ---------- light aggregate: out = relu((mean(gsrc[nbr]) + rsrc[node]) * s + t) ----
// 8 rows/wave, chunk-of-4 with per-row uniform skip; CSR state wave-uniform.
// In-place allowed: out may alias rsrc (own-row read data-depends before the write).
template<bool OUTF32>
__global__ __launch_bounds__(256) void spmmL_k(const unsigned short* __restrict__ gsrc,
                                               const unsigned short* __restrict__ rsrc,
                                               const int* __restrict__ rowptr,
                                               const int* __restrict__ nbr,
                                               const float* __restrict__ sc,
                                               const float* __restrict__ tc,
                                               void* __restrict__ out, int N, int E) {
  const int tid = threadIdx.x;
  const int lane = tid & 63;
  const int wu = __builtin_amdgcn_readfirstlane(tid >> 6);
  const int nb = blockIdx.x * 32 + wu * 8;

  int r0[8], d[8];
#pragma unroll
  for (int r = 0; r < 8; ++r) {
    const int i0 = min(nb + r, N);
    const int i1 = min(nb + r + 1, N);
    r0[r] = rowptr[i0];
    d[r] = (nb + r < N) ? (rowptr[i1] - r0[r]) : 0;
  }
  int dm = 0;
#pragma unroll
  for (int r = 0; r < 8; ++r) dm = max(dm, d[r]);

  float2 a[8];
#pragma unroll
  for (int r = 0; r < 8; ++r) a[r] = make_float2(0.f, 0.f);

  const int lofs = lane << 1;
  for (int e0 = 0; e0 < dm; e0 += 4) {
    unsigned int u[8][4];
#pragma unroll
    for (int r = 0; r < 8; ++r) {
      if (e0 < d[r]) {                                    // uniform scalar skip
#pragma unroll
        for (int j = 0; j < 4; ++j) {
          const int e = e0 + j;
          const int nv = nbr[min(r0[r] + e, E - 1)];      // uniform s_load (clamped)
          const int idx = (e < d[r]) ? nv : N;            // uniform -> sentinel row
          u[r][j] = *(const unsigned int*)(gsrc + ((long)idx << 7) + lofs);
        }
      }
    }
#pragma unroll
    for (int r = 0; r < 8; ++r) {
      if (e0 < d[r]) {
#pragma unroll
        for (int j = 0; j < 4; ++j) {
          a[r].x += bflo(u[r][j]);
          a[r].y += bfhi(u[r][j]);
        }
      }
    }
  }

  const float2 sv = *(const float2*)(sc + lofs);
  const float2 tv = *(const float2*)(tc + lofs);
#pragma unroll
  for (int r = 0; r < 8; ++r) {
    if (nb + r < N) {
      const float inv = 1.0f / fmaxf((float)d[r], 1.0f);
      const unsigned int ur = *(const unsigned int*)(rsrc + ((long)(nb + r) << 7) + lofs);
      float yx = fmaxf((a[r].x * inv + bflo(ur)) * sv.x + tv.x, 0.f);
      float yy = fmaxf((a[r].y * inv + bfhi(ur)) * sv.y + tv.y, 0.f);
      if (OUTF32) {
        *(float2*)((float*)out + (long)(nb + r) * 128 + lofs) = make_float2(yx, yy);
      } else {
        *(ushort2*)((unsigned short*)out + (long)(nb + r) * 128 + lofs) =
            pk(make_float2(yx, yy));
      }
    }
  }
}

extern "C" void kernel_launch(void* const* d_in, const int* in_sizes, int n_in,
                              void* d_out, int out_size, void* d_ws, size_t ws_size,
                              hipStream_t stream) {
  const float* x   = (const float*)d_in[0];
  const int*   ei  = (const int*)d_in[1];
  const float* W1l = (const float*)d_in[2];
  const float* b1  = (const float*)d_in[3];
  const float* W1r = (const float*)d_in[4];
  const float* g1  = (const float*)d_in[5];
  const float* be1 = (const float*)d_in[6];
  const float* rm1 = (const float*)d_in[7];
  const float* rv1 = (const float*)d_in[8];
  const float* W2l = (const float*)d_in[9];
  const float* b2  = (const float*)d_in[10];
  const float* W2r = (const float*)d_in[11];
  const float* g2  = (const float*)d_in[12];
  const float* be2 = (const float*)d_in[13];
  const float* rm2 = (const float*)d_in[14];
  const float* rv2 = (const float*)d_in[15];

  const int E = in_sizes[1] / 2;
  const int N = in_sizes[0] / 130;
  const int* src = ei;
  const int* dst = ei + E;

  // workspace carve (~158 MB)
  unsigned short* bufA = (unsigned short*)d_ws;            // P1l -> P2l (gather target, sentinel row N)
  unsigned short* bufB = bufA + (size_t)(N + 1) * 128;     // P1r -> h1 (in-place)
  unsigned short* bufC = bufB + (size_t)(N + 1) * 128;     // P2r
  unsigned short* wp1  = bufC + (size_t)N * 128;           // 5*8192
  unsigned short* wp2  = wp1 + 5 * 8192;                   // 4*8192
  float* s1 = (float*)(wp2 + 4 * 8192);
  float* t1 = s1 + 128;
  float* s2 = t1 + 128;
  float* t2 = s2 + 128;
  int* degi   = (int*)(t2 + 128);   // N (reused as cursor)
  int* rowptr = degi + N;           // N+1
  int* bsum   = rowptr + N + 1;     // 256
  int* nbr    = bsum + 256;         // E

  const int NZB = (N + 255) / 256;
  const int ngb = (N + 63) / 64;
  const int ecb = (E + 255) / 256;
  const int nsb = (N + 31) / 32;
  const int nb1k = (N + 1023) / 1024;

  // 1) setup: zero degi + 2 combined packs + bn_fold + sentinel
  hipLaunchKernelGGL(setup_k, dim3(NZB + 288 + 1), dim3(256), 0, stream,
                     g1, be1, rm1, rv1, b1, g2, be2, rm2, rv2, b2,
                     W1l, W1r, W2l, W2r, s1, t1, s2, t2,
                     wp1, wp2, bufA, degi, N, NZB);

  // 2) fused: P1l|P1r = x @ [W1l|W1r]  ||  edge count into degi
  hipLaunchKernelGGL(gemmc_k, dim3(ngb + ecb), dim3(256), 0, stream,
                     x, wp1, bufA, bufB, dst, degi, N, E, ngb);

  // 3) CSR: scan1 -> scan3' -> fill
  hipLaunchKernelGGL(scan1_k, dim3(nb1k), dim3(256), 0, stream, degi, rowptr, bsum, N);
  hipLaunchKernelGGL(scan3_k, dim3((N + 256) / 256), dim3(256), 0, stream,
                     rowptr, degi, bsum, N, E);
  hipLaunchKernelGGL(fill_k, dim3(ecb), dim3(256), 0, stream,
                     src, dst, degi, nbr, E);

  // 4) L1 aggregate: h1 = relu((mean(P1l[nbr]) + P1r)*s1 + t1')  (in-place over bufB)
  hipLaunchKernelGGL((spmmL_k<false>), dim3(nsb), dim3(256), 0, stream,
                     bufA, bufB, rowptr, nbr, s1, t1, (void*)bufB, N, E);
  // 5) L2 dense: P2l|P2r = h1 @ [W2l|W2r]
  hipLaunchKernelGGL(gemmB_k, dim3(ngb), dim3(256), 0, stream,
                     bufB, wp2, bufA, bufC, N);
  // 6) L2 aggregate: out = relu((mean(P2l[nbr]) + P2r)*s2 + t2') -> d_out fp32
  hipLaunchKernelGGL((spmmL_k<true>), dim3(nsb), dim3(256), 0, stream,
                     bufA, bufC, rowptr, nbr, s2, t2, d_out, N, E);
}